// Round 4
// baseline (288.297 us; speedup 1.0000x reference)
//
#include <hip/hip_runtime.h>

// q = rownorm( 1 / (1 + ||x - c||^2) ), ALPHA=1
// x: (262144, 256) f32 ; clusters: (256, 256) f32 ; out: (262144, 256) f32
//
// R4: R3 structure (full 128KB B in LDS once per block, register-double-
// buffered x prefetch) but 8 waves/block (512 thr) -> 2 waves/SIMD for TLP.
// R3's 4-wave block = 1 wave/SIMD exposed every LDS/VALU latency. NT stores
// keep the 256MB output stream from evicting x/B in L2/L3.

#define NROWS 262144
#define DDIM  256
#define KCL   256
#define WAVES 8
#define ROWS_PER_TILE (WAVES * 16)          // 128
#define TPB   8                             // tiles per block
#define GRID  (NROWS / ROWS_PER_TILE / TPB) // 256 blocks = 1/CU

using f32x4  = __attribute__((ext_vector_type(4))) float;
using s16x8  = __attribute__((ext_vector_type(8))) short;

__device__ inline unsigned short f2bf(float f) {
    // round-to-nearest-even f32 -> bf16
    unsigned int u = __float_as_uint(f);
    u += 0x7fffu + ((u >> 16) & 1u);
    return (unsigned short)(u >> 16);
}

// One wave per cluster row: convert to bf16, compute ||c||^2.
__global__ void prep_kernel(const float* __restrict__ clusters,
                            unsigned short* __restrict__ cb,
                            float* __restrict__ csq) {
    int k    = blockIdx.x;
    int lane = threadIdx.x;  // 64 threads
    const float* row = clusters + (size_t)k * DDIM;
    float4 a = *reinterpret_cast<const float4*>(row + lane * 4);
    ushort4 b;
    b.x = f2bf(a.x); b.y = f2bf(a.y); b.z = f2bf(a.z); b.w = f2bf(a.w);
    *reinterpret_cast<ushort4*>(cb + (size_t)k * DDIM + lane * 4) = b;
    float ss = a.x*a.x + a.y*a.y + a.z*a.z + a.w*a.w;
    #pragma unroll
    for (int m = 1; m < 64; m <<= 1) ss += __shfl_xor(ss, m);
    if (lane == 0) csq[k] = ss;
}

// 8 waves/block; wave owns 16 rows x 256 cols per tile.
// A-frag: lane holds x[row0 + (l&15)][s*32 + (l>>4)*8 + j], j=0..7
// B-frag: lane holds c[f*16 + (l&15)][s*32 + (l>>4)*8 + j]
// C/D   : col = l&15, row = (l>>4)*4 + reg   [verified layout, m89]
__global__ __launch_bounds__(512, 2) void fused_kernel(
    const float* __restrict__ x,
    const unsigned short* __restrict__ cb,
    const float* __restrict__ csq,
    float* __restrict__ out) {

    __shared__ char lds_b[KCL * DDIM * 2];   // 128 KB: full B, swizzled

    const int tid  = threadIdx.x;
    const int lane = tid & 63;
    const int wave = tid >> 6;               // 0..7
    const int c15  = lane & 15;
    const int kch  = lane >> 4;              // 0..3

    const int tile0 = blockIdx.x * TPB;

    // per-lane base: row ((tile0+t)*128 + wave*16 + c15), col kch*8
    auto xbase = [&](int t) -> const float* {
        return x + (size_t)((tile0 + t) * ROWS_PER_TILE + wave * 16 + c15) * DDIM + kch * 8;
    };

    f32x4 stA[16], stB[16];

    // ---- issue first two tiles' x loads (in flight during B staging) ----
    #pragma unroll
    for (int i = 0; i < 16; ++i)
        stA[i] = *reinterpret_cast<const f32x4*>(xbase(0) + (i >> 1) * 32 + (i & 1) * 4);
    #pragma unroll
    for (int i = 0; i < 16; ++i)
        stB[i] = *reinterpret_cast<const f32x4*>(xbase(1) + (i >> 1) * 32 + (i & 1) * 4);

    // ---- stage full B into LDS (linear dest, swizzled global source) ----
    #pragma unroll
    for (int it = 0; it < 16; ++it) {
        int slot = it * 8192 + tid * 16;
        int src  = slot ^ (((slot >> 9) & 7) << 4);
        __builtin_amdgcn_global_load_lds(
            (const __attribute__((address_space(1))) unsigned int*)((const char*)cb + src),
            (__attribute__((address_space(3))) unsigned int*)(lds_b + slot),
            16, 0, 0);
    }

    // csq fragment for the epilogue (block-invariant)
    float cs[16];
    #pragma unroll
    for (int f = 0; f < 16; ++f) cs[f] = csq[f * 16 + c15];

    __syncthreads();   // drains vmcnt; B ready

    s16x8 afrag[8];

    auto convert = [&](const f32x4* st, float& xsq) {
        xsq = 0.f;
        #pragma unroll
        for (int s = 0; s < 8; ++s) {
            f32x4 xa = st[2 * s], xb = st[2 * s + 1];
            xsq += xa[0]*xa[0] + xa[1]*xa[1] + xa[2]*xa[2] + xa[3]*xa[3]
                 + xb[0]*xb[0] + xb[1]*xb[1] + xb[2]*xb[2] + xb[3]*xb[3];
            afrag[s][0] = (short)f2bf(xa[0]); afrag[s][1] = (short)f2bf(xa[1]);
            afrag[s][2] = (short)f2bf(xa[2]); afrag[s][3] = (short)f2bf(xa[3]);
            afrag[s][4] = (short)f2bf(xb[0]); afrag[s][5] = (short)f2bf(xb[1]);
            afrag[s][6] = (short)f2bf(xb[2]); afrag[s][7] = (short)f2bf(xb[3]);
        }
    };

    auto compute_store = [&](int t, float xsq) {
        f32x4 acc[16];
        #pragma unroll
        for (int f = 0; f < 16; ++f) acc[f] = (f32x4){0.f, 0.f, 0.f, 0.f};

        #pragma unroll
        for (int f = 0; f < 16; ++f) {
            #pragma unroll
            for (int s = 0; s < 8; ++s) {
                int ba = (f * 16 + c15) * 512 + s * 64 + kch * 16;
                ba ^= ((c15 & 7) << 4);
                s16x8 bfrag = *reinterpret_cast<const s16x8*>(lds_b + ba);
                acc[f] = __builtin_amdgcn_mfma_f32_16x16x32_bf16(afrag[s], bfrag,
                                                                 acc[f], 0, 0, 0);
            }
        }

        // combine the 4 kch partials of ||x||^2 (lane l -> row l&15)
        xsq += __shfl_xor(xsq, 16);
        xsq += __shfl_xor(xsq, 32);

        const int row0t = (tile0 + t) * ROWS_PER_TILE + wave * 16;
        #pragma unroll
        for (int r = 0; r < 4; ++r) {
            float xr = __shfl(xsq, kch * 4 + r);
            float s = 0.f;
            #pragma unroll
            for (int f = 0; f < 16; ++f) {
                float d2 = xr - 2.0f * acc[f][r] + cs[f];
                float qv = 1.0f / (1.0f + d2);   // ALPHA=1 -> exponent == 1
                acc[f][r] = qv;
                s += qv;
            }
            s += __shfl_xor(s, 1);
            s += __shfl_xor(s, 2);
            s += __shfl_xor(s, 4);
            s += __shfl_xor(s, 8);
            float inv = 1.0f / s;
            const size_t orow = (size_t)(row0t + kch * 4 + r) * KCL;
            #pragma unroll
            for (int f = 0; f < 16; ++f) {
                __builtin_nontemporal_store(acc[f][r] * inv, &out[orow + f * 16 + c15]);
            }
        }
    };

    #pragma unroll 1
    for (int t = 0; t < TPB; t += 2) {
        float xsqA, xsqB;
        convert(stA, xsqA);                 // waits stA loads (long in flight)
        if (t + 2 < TPB) {                  // refill stA for tile t+2
            #pragma unroll
            for (int i = 0; i < 16; ++i)
                stA[i] = *reinterpret_cast<const f32x4*>(xbase(t + 2) + (i >> 1) * 32 + (i & 1) * 4);
        }
        compute_store(t, xsqA);             // MFMA/LDS hide stA(t+2) latency

        convert(stB, xsqB);
        if (t + 3 < TPB) {                  // refill stB for tile t+3
            #pragma unroll
            for (int i = 0; i < 16; ++i)
                stB[i] = *reinterpret_cast<const f32x4*>(xbase(t + 3) + (i >> 1) * 32 + (i & 1) * 4);
        }
        compute_store(t + 1, xsqB);
    }
}

extern "C" void kernel_launch(void* const* d_in, const int* in_sizes, int n_in,
                              void* d_out, int out_size, void* d_ws, size_t ws_size,
                              hipStream_t stream) {
    const float* x        = (const float*)d_in[0];
    const float* clusters = (const float*)d_in[1];
    float* out = (float*)d_out;

    // ws layout: [0, 128KB) clusters as bf16 ; [128KB, +1KB) c_sq f32
    unsigned short* cb  = (unsigned short*)d_ws;
    float*          csq = (float*)((char*)d_ws + (size_t)KCL * DDIM * sizeof(unsigned short));

    prep_kernel<<<KCL, 64, 0, stream>>>(clusters, cb, csq);
    fused_kernel<<<GRID, 512, 0, stream>>>(x, cb, csq, out);
}